// Round 17
// baseline (1445.728 us; speedup 1.0000x reference)
//
#include <hip/hip_runtime.h>
#include <math.h>

#define TSTEPS 8
#define FDIM 128
#define HDIM 128
#define ODIM 64
#define GDIM 512
#define BUCKR 2048
#define BUCKR_SHIFT 11
#define BPT 32   // blocks per timestep in bin_count / bin_scatter

typedef __attribute__((ext_vector_type(4))) float f32x4;
typedef __attribute__((ext_vector_type(8))) short s8;

__device__ __forceinline__ float sigmf(float x) { return 1.0f / (1.0f + __expf(-x)); }
__device__ __forceinline__ float fast_tanh(float x) {
    float ax = fabsf(x);
    float ez = __expf(2.f * ax);
    float r = 1.f - 2.f / (ez + 1.f);
    return copysignf(r, x);
}

__device__ __forceinline__ ushort f2bf(float x) {
    uint u = __float_as_uint(x);
    u += 0x7FFFu + ((u >> 16) & 1u);
    return (ushort)(u >> 16);
}
__device__ __forceinline__ float bf2f(ushort h) { return __uint_as_float(((uint)h) << 16); }

// ---------------- setup kernels ----------------

__global__ void prep_lstm_w(const float* __restrict__ wih, const float* __restrict__ whh,
                            const float* __restrict__ bih, const float* __restrict__ bhh,
                            float* __restrict__ wcat, float* __restrict__ bsum) {
    int idx = blockIdx.x * 256 + threadIdx.x;
    if (idx < 256 * GDIM) {
        int k = idx >> 9;
        int col = idx & 511;
        float v = (k < HDIM) ? wih[col * HDIM + k] : whh[col * HDIM + (k - HDIM)];
        wcat[idx] = v;
        if (k == 0) bsum[col] = bih[col] + bhh[col];
    }
}

// pack B [K][NC] f32 (k-major) into MFMA-frag order, split hi/lo bf16 (weights only).
__global__ void pack_b(const float* __restrict__ B, int K, int NC,
                       uint* __restrict__ hi, uint* __restrict__ lo) {
    int total = (K / 32) * (NC / 16) * 256;
    int idx = blockIdx.x * 256 + threadIdx.x;
    if (idx >= total) return;
    int d = idx & 3, l = (idx >> 2) & 63, t = idx >> 8;
    int NT = NC / 16;
    int kt = t / NT, nt = t % NT;
    int k = kt * 32 + (l >> 4) * 8 + d * 2;
    int col = nt * 16 + (l & 15);
    float va = B[(size_t)k * NC + col];
    float vb = B[(size_t)(k + 1) * NC + col];
    ushort ha = f2bf(va), hb = f2bf(vb);
    float ra = va - bf2f(ha), rb = vb - bf2f(hb);
    hi[idx] = (uint)ha | ((uint)hb << 16);
    lo[idx] = (uint)f2bf(ra) | ((uint)f2bf(rb) << 16);
}

__global__ void zero_int(int* __restrict__ p, int n) {
    int idx = blockIdx.x * 256 + threadIdx.x;
    if (idx < n) p[idx] = 0;
}

// ---------------- bucketed CSR build ----------------

__global__ __launch_bounds__(256) void bin_count(const int* __restrict__ edges,
                                                 int* __restrict__ gcount,
                                                 int E, int N, int nbuck) {
    __shared__ int h[1024];
    int tid = threadIdx.x;
    int t = blockIdx.x >> 5, b = blockIdx.x & 31;
    int ce = (E + BPT - 1) / BPT;
    int e0 = b * ce, e1 = min(e0 + ce, E);
    for (int i = tid; i < 1024; i += 256) h[i] = 0;
    __syncthreads();
    const int* dstp = edges + (size_t)t * 2 * E + E;
    for (int i = e0 + tid; i < e1; i += 256) {
        int gid = t * N + dstp[i];
        atomicAdd(&h[gid >> BUCKR_SHIFT], 1);
    }
    __syncthreads();
    for (int i = tid; i < nbuck; i += 256) {
        int c = h[i];
        if (c) atomicAdd(&gcount[i], c);
    }
}

__global__ __launch_bounds__(1024) void scan_buckets(const int* __restrict__ gcount,
                                                     int* __restrict__ bucket_start,
                                                     int* __restrict__ bucket_cursor,
                                                     int nbuck, int* __restrict__ row_start,
                                                     int nTotal, int totalE) {
    __shared__ int s[1024];
    int t = threadIdx.x;
    int own = (t < nbuck) ? gcount[t] : 0;
    s[t] = own; __syncthreads();
    for (int off = 1; off < 1024; off <<= 1) {
        int add = (t >= off) ? s[t - off] : 0;
        __syncthreads();
        s[t] += add;
        __syncthreads();
    }
    if (t < nbuck) {
        int excl = s[t] - own;
        bucket_start[t] = excl;
        bucket_cursor[t] = excl;
    }
    if (t == 0) {
        bucket_start[nbuck] = totalE;
        row_start[nTotal] = totalE;
    }
}

__global__ __launch_bounds__(256) void bin_scatter(const int* __restrict__ edges,
                                                   int* __restrict__ bucket_cursor,
                                                   uint2* __restrict__ staged,
                                                   int E, int N, int nbuck) {
    __shared__ int h[1024];
    __shared__ int base[1024];
    int tid = threadIdx.x;
    int t = blockIdx.x >> 5, b = blockIdx.x & 31;
    int ce = (E + BPT - 1) / BPT;
    int e0 = b * ce, e1 = min(e0 + ce, E);
    for (int i = tid; i < 1024; i += 256) h[i] = 0;
    __syncthreads();
    const int* srcp = edges + (size_t)t * 2 * E;
    const int* dstp = srcp + E;
    for (int i = e0 + tid; i < e1; i += 256) {
        int gid = t * N + dstp[i];
        atomicAdd(&h[gid >> BUCKR_SHIFT], 1);
    }
    __syncthreads();
    for (int i = tid; i < nbuck; i += 256) {
        int c = h[i];
        if (c) base[i] = atomicAdd(&bucket_cursor[i], c);
        h[i] = 0;
    }
    __syncthreads();
    for (int i = e0 + tid; i < e1; i += 256) {
        int sgid = t * N + srcp[i];
        int dgid = t * N + dstp[i];
        int bk = dgid >> BUCKR_SHIFT;
        int loc = atomicAdd(&h[bk], 1);
        staged[base[bk] + loc] = make_uint2((uint)sgid, (uint)dgid);
    }
}

__global__ __launch_bounds__(256) void bin_csr(const uint2* __restrict__ staged,
                                               const int* __restrict__ bucket_start,
                                               int* __restrict__ row_start,
                                               int* __restrict__ csr_src,
                                               float* __restrict__ dinv, int nTotal) {
    __shared__ int cnt[BUCKR];
    __shared__ int part[256];
    int tid = threadIdx.x;
    int node0 = blockIdx.x << BUCKR_SHIFT;
    int nloc = min(BUCKR, nTotal - node0);
    int ebase = bucket_start[blockIdx.x], eend = bucket_start[blockIdx.x + 1];

    for (int j = tid; j < BUCKR; j += 256) cnt[j] = 0;
    __syncthreads();
    for (int e = ebase + tid; e < eend; e += 256)
        atomicAdd(&cnt[(int)staged[e].y - node0], 1);
    __syncthreads();

    int s = 0;
    #pragma unroll
    for (int k = 0; k < 8; k++) s += cnt[tid * 8 + k];
    part[tid] = s; __syncthreads();
    for (int off = 1; off < 256; off <<= 1) {
        int add = (tid >= off) ? part[tid - off] : 0;
        __syncthreads();
        part[tid] += add;
        __syncthreads();
    }
    int run = part[tid] - s;
    #pragma unroll
    for (int k = 0; k < 8; k++) {
        int j = tid * 8 + k;
        int c = cnt[j];
        if (j < nloc) {
            row_start[node0 + j] = ebase + run;
            dinv[node0 + j] = rsqrtf((float)(c + 1));
        }
        cnt[j] = run;
        run += c;
    }
    __syncthreads();
    for (int e = ebase + tid; e < eend; e += 256) {
        uint2 ed = staged[e];
        int d = (int)ed.y - node0;
        int pos = ebase + atomicAdd(&cnt[d], 1);
        csr_src[pos] = (int)ed.x;
    }
}

// ---------------- gather aggregation, one timestep per dispatch ----------------
// hi-only bf16 in and out.

__global__ __launch_bounds__(256) void agg_gather_t(
    const int* __restrict__ row_start, const int* __restrict__ csr_src,
    const uint* __restrict__ xh,
    const float* __restrict__ dinv, const float* __restrict__ bias,
    uint* __restrict__ ohi, int rowOff, int outRowOff, int nloc)
{
    int w = (blockIdx.x * 256 + threadIdx.x) >> 6;
    int lane = threadIdx.x & 63;
    if (w >= nloc) return;
    int wg = rowOff + w;
    float dr = dinv[wg];
    float cc = dr * dr;
    uint shv = xh[(size_t)wg * 64 + lane];
    float a0 = __uint_as_float(shv << 16) * cc;
    float a1 = __uint_as_float(shv & 0xFFFF0000u) * cc;
    int e = row_start[wg], e1 = row_start[wg + 1];
    for (; e + 4 <= e1; e += 4) {
        int s0 = csr_src[e], s1 = csr_src[e + 1], s2 = csr_src[e + 2], s3 = csr_src[e + 3];
        float c0 = dinv[s0] * dr, c1 = dinv[s1] * dr, c2 = dinv[s2] * dr, c3 = dinv[s3] * dr;
        uint u0 = xh[(size_t)s0 * 64 + lane];
        uint u1 = xh[(size_t)s1 * 64 + lane];
        uint u2 = xh[(size_t)s2 * 64 + lane];
        uint u3 = xh[(size_t)s3 * 64 + lane];
        a0 = fmaf(__uint_as_float(u0 << 16), c0, a0);
        a1 = fmaf(__uint_as_float(u0 & 0xFFFF0000u), c0, a1);
        a0 = fmaf(__uint_as_float(u1 << 16), c1, a0);
        a1 = fmaf(__uint_as_float(u1 & 0xFFFF0000u), c1, a1);
        a0 = fmaf(__uint_as_float(u2 << 16), c2, a0);
        a1 = fmaf(__uint_as_float(u2 & 0xFFFF0000u), c2, a1);
        a0 = fmaf(__uint_as_float(u3 << 16), c3, a0);
        a1 = fmaf(__uint_as_float(u3 & 0xFFFF0000u), c3, a1);
    }
    for (; e < e1; e++) {
        int s = csr_src[e];
        float cf = dinv[s] * dr;
        uint u = xh[(size_t)s * 64 + lane];
        a0 = fmaf(__uint_as_float(u << 16), cf, a0);
        a1 = fmaf(__uint_as_float(u & 0xFFFF0000u), cf, a1);
    }
    float2 b = ((const float2*)bias)[lane];
    a0 = fmaxf(a0 + b.x, 0.f);
    a1 = fmaxf(a1 + b.y, 0.f);
    ohi[(size_t)(wg - outRowOff) * 64 + lane] = (uint)f2bf(a0) | ((uint)f2bf(a1) << 16);
}

// ---------------- MFMA GEMM: [M,128] @ [128,128] -> bf16 hi-only out ----------------
// 512 threads, 128 rows/block, 8 waves = 4(M) x 2(N). A hi-only; B hi+lo (2 MFMAs).

template<bool SPLITSRC>
__global__ __launch_bounds__(512) void gemm_mfma128(
    const float* __restrict__ A32, const ushort* __restrict__ Ahi,
    const uint4* __restrict__ Bhi, const uint4* __restrict__ Blo,
    ushort* __restrict__ Chi, int nrows)
{
    __shared__ ushort AsH[128][136];
    const int r0 = blockIdx.x * 128;
    const int tid = threadIdx.x;

    if (SPLITSRC) {
        for (int v = tid; v < 128 * 16; v += 512) {
            int row = v >> 4, seg = v & 15;
            uint4 h = make_uint4(0, 0, 0, 0);
            if (r0 + row < nrows)
                h = *(const uint4*)(Ahi + (size_t)(r0 + row) * 128 + seg * 8);
            *(uint4*)&AsH[row][seg * 8] = h;
        }
    } else {
        for (int v = tid; v < 128 * 16; v += 512) {
            int row = v >> 4, seg = v & 15;
            float4 a = make_float4(0.f, 0.f, 0.f, 0.f), b = a;
            if (r0 + row < nrows) {
                const float4* src = (const float4*)A32 + (size_t)(r0 + row) * 32 + seg * 2;
                a = src[0]; b = src[1];
            }
            float vv[8] = {a.x, a.y, a.z, a.w, b.x, b.y, b.z, b.w};
            uint hh[4];
            #pragma unroll
            for (int i = 0; i < 4; i++)
                hh[i] = (uint)f2bf(vv[2 * i]) | ((uint)f2bf(vv[2 * i + 1]) << 16);
            *(uint4*)&AsH[row][seg * 8] = make_uint4(hh[0], hh[1], hh[2], hh[3]);
        }
    }
    __syncthreads();

    const int l = tid & 63, w = tid >> 6;
    const int wm = w & 3, wn = w >> 2;
    const int lrow = l & 15, lk = (l >> 4) * 8;

    f32x4 acc[2][4];
    #pragma unroll
    for (int m = 0; m < 2; m++)
        #pragma unroll
        for (int p = 0; p < 4; p++) acc[m][p] = (f32x4){0.f, 0.f, 0.f, 0.f};

    #pragma unroll
    for (int kt = 0; kt < 4; kt++) {
        uint4 BH[4], BL[4];
        #pragma unroll
        for (int p = 0; p < 4; p++) {
            int nt = 4 * wn + p;
            BH[p] = Bhi[(kt * 8 + nt) * 64 + l];
            BL[p] = Blo[(kt * 8 + nt) * 64 + l];
        }
        s8 aH[2];
        #pragma unroll
        for (int m = 0; m < 2; m++) {
            int row = (2 * wm + m) * 16 + lrow;
            aH[m] = *(const s8*)&AsH[row][kt * 32 + lk];
        }
        #pragma unroll
        for (int p = 0; p < 4; p++) {
            s8 bh = __builtin_bit_cast(s8, BH[p]);
            s8 bl = __builtin_bit_cast(s8, BL[p]);
            #pragma unroll
            for (int m = 0; m < 2; m++) {
                acc[m][p] = __builtin_amdgcn_mfma_f32_16x16x32_bf16(aH[m], bh, acc[m][p], 0, 0, 0);
                acc[m][p] = __builtin_amdgcn_mfma_f32_16x16x32_bf16(aH[m], bl, acc[m][p], 0, 0, 0);
            }
        }
    }

    // repack C (hi only) through LDS for coalesced stores
    __syncthreads();
    const int lr4 = (l >> 4) * 4;
    #pragma unroll
    for (int m = 0; m < 2; m++) {
        #pragma unroll
        for (int p = 0; p < 4; p++) {
            int col = (4 * wn + p) * 16 + lrow;
            #pragma unroll
            for (int r = 0; r < 4; r++) {
                int row = (2 * wm + m) * 16 + lr4 + r;
                AsH[row][col] = f2bf(acc[m][p][r]);
            }
        }
    }
    __syncthreads();
    for (int v = tid; v < 128 * 16; v += 512) {
        int row = v >> 4, seg = v & 15;
        if (r0 + row < nrows)
            *(uint4*)(Chi + (size_t)(r0 + row) * 128 + seg * 8) = *(const uint4*)&AsH[row][seg * 8];
    }
}

// ---------------- multi-timestep LSTM: 4 t per dispatch; LAST fuses head + outputs ----
// 512 threads, 64 rows/block, 8 waves. c in registers across all 4 t; h hands off via LDS.

template<bool LAST>
__global__ __launch_bounds__(512, 2) void lstm_step4(
    const ushort* __restrict__ Ehi_all,   // [8N][128] hi-only
    ushort* __restrict__ Hhi,
    const uint4* __restrict__ Bhi, const uint4* __restrict__ Blo,
    const float* __restrict__ bsum, float* __restrict__ cbuf,
    const uint4* __restrict__ Whi, const uint4* __restrict__ Wlo,
    const float* __restrict__ bout,
    float* __restrict__ outp, float* __restrict__ outh, float* __restrict__ outc,
    int tbase, int tcount, int nrows)
{
    __shared__ ushort AsH[64][264];
    const int r0 = blockIdx.x * 64;
    const int tid = threadIdx.x;
    const int l = tid & 63, w = tid >> 6;          // w in 0..7
    const int lrow = l & 15, lk = (l >> 4) * 8, lr4 = (l >> 4) * 4;
    const int hh = 16 * w + lrow;

    // initial stage: e(tbase) cols 0..127, h cols 128..255
    for (int v = tid; v < 64 * 32; v += 512) {
        int row = v >> 5, seg = v & 31;
        uint4 h = make_uint4(0, 0, 0, 0);
        if (r0 + row < nrows) {
            if (seg < 16)
                h = *(const uint4*)(Ehi_all + ((size_t)tbase * nrows + r0 + row) * 128 + seg * 8);
            else
                h = *(const uint4*)(Hhi + (size_t)(r0 + row) * 128 + (seg - 16) * 8);
        }
        *(uint4*)&AsH[row][seg * 8] = h;
    }

    // c into registers (held for all tcount steps)
    float creg[4][4];
    #pragma unroll
    for (int m = 0; m < 4; m++)
        #pragma unroll
        for (int r = 0; r < 4; r++) {
            int row = m * 16 + lr4 + r;
            creg[m][r] = (r0 + row < nrows) ? cbuf[(size_t)(r0 + row) * HDIM + hh] : 0.f;
        }

    float bgate[4];
    #pragma unroll
    for (int q = 0; q < 4; q++) bgate[q] = bsum[q * 128 + hh];

    __syncthreads();

    #pragma unroll 1
    for (int ti = 0; ti < tcount; ti++) {
        f32x4 acc[4][4];
        #pragma unroll
        for (int m = 0; m < 4; m++)
            #pragma unroll
            for (int q = 0; q < 4; q++)
                acc[m][q] = (f32x4){bgate[q], bgate[q], bgate[q], bgate[q]};

        #pragma unroll 2
        for (int kt = 0; kt < 8; kt++) {
            uint4 BH[4], BL[4];
            #pragma unroll
            for (int q = 0; q < 4; q++) {
                int nt = 8 * q + w;
                BH[q] = Bhi[((size_t)kt * 32 + nt) * 64 + l];
                BL[q] = Blo[((size_t)kt * 32 + nt) * 64 + l];
            }
            s8 aH[4];
            #pragma unroll
            for (int m = 0; m < 4; m++)
                aH[m] = *(const s8*)&AsH[m * 16 + lrow][kt * 32 + lk];
            #pragma unroll
            for (int q = 0; q < 4; q++) {
                s8 bh = __builtin_bit_cast(s8, BH[q]);
                s8 bl = __builtin_bit_cast(s8, BL[q]);
                #pragma unroll
                for (int m = 0; m < 4; m++) {
                    acc[m][q] = __builtin_amdgcn_mfma_f32_16x16x32_bf16(aH[m], bh, acc[m][q], 0, 0, 0);
                    acc[m][q] = __builtin_amdgcn_mfma_f32_16x16x32_bf16(aH[m], bl, acc[m][q], 0, 0, 0);
                }
            }
        }
        __syncthreads();   // all LDS reads for this t done

        bool lastT = (ti == tcount - 1);
        #pragma unroll
        for (int m = 0; m < 4; m++) {
            #pragma unroll
            for (int r = 0; r < 4; r++) {
                int row = m * 16 + lr4 + r;
                float gi = acc[m][0][r], gf = acc[m][1][r];
                float gg = acc[m][2][r], go = acc[m][3][r];
                float cn = sigmf(gf) * creg[m][r] + sigmf(gi) * fast_tanh(gg);
                float hn = sigmf(go) * fast_tanh(cn);
                creg[m][r] = cn;
                ushort hb = f2bf(hn);
                AsH[row][128 + hh] = hb;
                if (r0 + row < nrows) {
                    size_t o = (size_t)(r0 + row) * HDIM + hh;
                    if (lastT) {
                        Hhi[o] = hb;
                        cbuf[o] = cn;
                        if (LAST) { outh[o] = hn; outc[o] = cn; }
                    }
                }
            }
        }
        // stage next e slice into cols 0..127 (disjoint from h cols)
        if (!lastT) {
            int tn = tbase + ti + 1;
            for (int v = tid; v < 64 * 16; v += 512) {
                int row = v >> 4, seg = v & 15;
                uint4 h = make_uint4(0, 0, 0, 0);
                if (r0 + row < nrows)
                    h = *(const uint4*)(Ehi_all + ((size_t)tn * nrows + r0 + row) * 128 + seg * 8);
                *(uint4*)&AsH[row][seg * 8] = h;
            }
        }
        __syncthreads();
    }

    if (LAST) {
        // head: out[64,64] = h_T @ Wout + bout (h_T in LDS cols 128..255)
        if (w < 4) {
            f32x4 hacc[4];
            {
                float b = bout[w * 16 + lrow];
                #pragma unroll
                for (int m = 0; m < 4; m++) hacc[m] = (f32x4){b, b, b, b};
            }
            #pragma unroll
            for (int kt = 0; kt < 4; kt++) {
                uint4 BH = Whi[(kt * 4 + w) * 64 + l];
                uint4 BL = Wlo[(kt * 4 + w) * 64 + l];
                s8 aH[4];
                #pragma unroll
                for (int m = 0; m < 4; m++)
                    aH[m] = *(const s8*)&AsH[m * 16 + lrow][128 + kt * 32 + lk];
                s8 bh = __builtin_bit_cast(s8, BH);
                s8 bl = __builtin_bit_cast(s8, BL);
                #pragma unroll
                for (int m = 0; m < 4; m++) {
                    hacc[m] = __builtin_amdgcn_mfma_f32_16x16x32_bf16(aH[m], bh, hacc[m], 0, 0, 0);
                    hacc[m] = __builtin_amdgcn_mfma_f32_16x16x32_bf16(aH[m], bl, hacc[m], 0, 0, 0);
                }
            }
            #pragma unroll
            for (int m = 0; m < 4; m++) {
                #pragma unroll
                for (int r = 0; r < 4; r++) {
                    int row = r0 + m * 16 + lr4 + r;
                    if (row < nrows)
                        outp[(size_t)row * ODIM + w * 16 + lrow] = hacc[m][r];
                }
            }
        }
    }
}

// ---------------- launch ----------------

static inline int cdiv(long long a, long long b) { return (int)((a + b - 1) / b); }

extern "C" void kernel_launch(void* const* d_in, const int* in_sizes, int n_in,
                              void* d_out, int out_size, void* d_ws, size_t ws_size,
                              hipStream_t stream) {
    const float* x_seq = (const float*)d_in[0];
    const int*   edges = (const int*)d_in[1];
    const float* W1    = (const float*)d_in[2];
    const float* b1    = (const float*)d_in[3];
    const float* W2    = (const float*)d_in[4];
    const float* b2    = (const float*)d_in[5];
    const float* Wih   = (const float*)d_in[6];
    const float* Whh   = (const float*)d_in[7];
    const float* bih   = (const float*)d_in[8];
    const float* bhh   = (const float*)d_in[9];
    const float* Wout  = (const float*)d_in[10];
    const float* bout  = (const float*)d_in[11];
    float* out = (float*)d_out;

    const int N = in_sizes[0] / (TSTEPS * FDIM);   // 50000
    const int E = in_sizes[1] / (2 * TSTEPS);      // 600000
    const int NT8 = TSTEPS * N;                    // 400000
    const size_t NP = ((size_t)NT8 + 255) & ~(size_t)255;
    const int NBUCK = cdiv(NT8, BUCKR);            // 196
    const size_t nf = (size_t)N * FDIM;
    const int E8 = TSTEPS * E;

    // workspace layout
    float* ws = (float*)d_ws;
    float* dinv = ws;                              // NP f32
    float* wcat = dinv + NP;                       // 256*512
    float* bsum = wcat + 131072;                   // 512
    uint* pW1hi = (uint*)(bsum + 512);             // 8192 each
    uint* pW1lo = pW1hi + 8192;
    uint* pW2hi = pW1lo + 8192;
    uint* pW2lo = pW2hi + 8192;
    uint* pWchi = pW2lo + 8192;                    // 65536 each
    uint* pWclo = pWchi + 65536;
    uint* pWohi = pWclo + 65536;                   // 4096 each
    uint* pWolo = pWohi + 4096;
    float* cbuf = (float*)(pWolo + 4096);          // [N][128] f32
    ushort* hhi = (ushort*)(cbuf + nf);            // [N][128] bf16
    ushort* ehi = hhi + nf;                        // [8N][128] hi-only (full)
    ushort* xwhi = ehi + (size_t)NT8 * 128;        // [8N][128] hi-only
    ushort* h1hi = xwhi + (size_t)NT8 * 128;       // [8N][128] hi-only
    uint2* staged  = (uint2*)(h1hi + (size_t)NT8 * 128);  // 8E uint2
    int* csr_src   = (int*)(staged + E8);                 // 8E
    int* row_start = csr_src + E8;                        // NT8+1 (pad NP+2)
    int* gcount    = row_start + NP + 2;                  // 1024
    int* bucket_start  = gcount + 1024;                   // 1026
    int* bucket_cursor = bucket_start + 1026;             // 1024

    // weights prep
    prep_lstm_w<<<cdiv(256 * GDIM, 256), 256, 0, stream>>>(Wih, Whh, bih, bhh, wcat, bsum);
    pack_b<<<32, 256, 0, stream>>>(W1, 128, 128, pW1hi, pW1lo);
    pack_b<<<32, 256, 0, stream>>>(W2, 128, 128, pW2hi, pW2lo);
    pack_b<<<256, 256, 0, stream>>>(wcat, 256, GDIM, pWchi, pWclo);
    pack_b<<<16, 256, 0, stream>>>(Wout, 128, ODIM, pWohi, pWolo);

    // zero c (f32, nf ints) + h hi (nf/2 ints)
    zero_int<<<cdiv((long long)nf + nf / 2, 256), 256, 0, stream>>>((int*)cbuf, (int)(nf + nf / 2));

    // bucketed CSR build
    zero_int<<<4, 256, 0, stream>>>(gcount, 1024);
    bin_count<<<TSTEPS * BPT, 256, 0, stream>>>(edges, gcount, E, N, NBUCK);
    scan_buckets<<<1, 1024, 0, stream>>>(gcount, bucket_start, bucket_cursor, NBUCK,
                                         row_start, NT8, E8);
    bin_scatter<<<TSTEPS * BPT, 256, 0, stream>>>(edges, bucket_cursor, staged, E, N, NBUCK);
    bin_csr<<<NBUCK, 256, 0, stream>>>(staged, bucket_start, row_start, csr_src, dinv, NT8);

    const int gagrid = cdiv((long long)N * 64, 256);

    // layer 1: batched GEMM (hi-only out), per-timestep gathers
    gemm_mfma128<false><<<cdiv(NT8, 128), 512, 0, stream>>>(
        x_seq, nullptr, (const uint4*)pW1hi, (const uint4*)pW1lo, xwhi, NT8);
    for (int t = 0; t < TSTEPS; t++)
        agg_gather_t<<<gagrid, 256, 0, stream>>>(
            row_start, csr_src, (const uint*)xwhi, dinv, b1,
            (uint*)h1hi, t * N, 0, N);

    // layer 2: batched GEMM (hi-only out)
    gemm_mfma128<true><<<cdiv(NT8, 128), 512, 0, stream>>>(
        nullptr, h1hi, (const uint4*)pW2hi, (const uint4*)pW2lo, xwhi, NT8);

    // agg2 for all timesteps into the full e buffer
    for (int t = 0; t < TSTEPS; t++)
        agg_gather_t<<<gagrid, 256, 0, stream>>>(
            row_start, csr_src, (const uint*)xwhi, dinv, b2,
            (uint*)ehi, t * N, 0, N);

    // LSTM: 4 timesteps per dispatch, c in registers, h via LDS
    float* out_h = out + (size_t)N * ODIM;
    float* out_c = out_h + (size_t)N * HDIM;
    lstm_step4<false><<<cdiv(N, 64), 512, 0, stream>>>(
        ehi, hhi, (const uint4*)pWchi, (const uint4*)pWclo, bsum, cbuf,
        nullptr, nullptr, nullptr, nullptr, nullptr, nullptr, 0, 4, N);
    lstm_step4<true><<<cdiv(N, 64), 512, 0, stream>>>(
        ehi, hhi, (const uint4*)pWchi, (const uint4*)pWclo, bsum, cbuf,
        (const uint4*)pWohi, (const uint4*)pWolo, bout,
        out, out_h, out_c, 4, 4, N);
}

// Round 18
// 1359.108 us; speedup vs baseline: 1.0637x; 1.0637x over previous
//
#include <hip/hip_runtime.h>
#include <math.h>

#define TSTEPS 8
#define FDIM 128
#define HDIM 128
#define ODIM 64
#define GDIM 512
#define BUCKR 2048
#define BUCKR_SHIFT 11
#define BPT 32   // blocks per timestep in bin_count / bin_scatter

typedef __attribute__((ext_vector_type(4))) float f32x4;
typedef __attribute__((ext_vector_type(8))) short s8;

__device__ __forceinline__ float sigmf(float x) { return 1.0f / (1.0f + __expf(-x)); }
__device__ __forceinline__ float fast_tanh(float x) {
    float ax = fabsf(x);
    float ez = __expf(2.f * ax);
    float r = 1.f - 2.f / (ez + 1.f);
    return copysignf(r, x);
}

__device__ __forceinline__ ushort f2bf(float x) {
    uint u = __float_as_uint(x);
    u += 0x7FFFu + ((u >> 16) & 1u);
    return (ushort)(u >> 16);
}
__device__ __forceinline__ float bf2f(ushort h) { return __uint_as_float(((uint)h) << 16); }

// ---------------- setup kernels ----------------

__global__ void prep_lstm_w(const float* __restrict__ wih, const float* __restrict__ whh,
                            const float* __restrict__ bih, const float* __restrict__ bhh,
                            float* __restrict__ wcat, float* __restrict__ bsum) {
    int idx = blockIdx.x * 256 + threadIdx.x;
    if (idx < 256 * GDIM) {
        int k = idx >> 9;
        int col = idx & 511;
        float v = (k < HDIM) ? wih[col * HDIM + k] : whh[col * HDIM + (k - HDIM)];
        wcat[idx] = v;
        if (k == 0) bsum[col] = bih[col] + bhh[col];
    }
}

// pack B [K][NC] f32 (k-major) into MFMA-frag order, split hi/lo bf16 (weights only).
__global__ void pack_b(const float* __restrict__ B, int K, int NC,
                       uint* __restrict__ hi, uint* __restrict__ lo) {
    int total = (K / 32) * (NC / 16) * 256;
    int idx = blockIdx.x * 256 + threadIdx.x;
    if (idx >= total) return;
    int d = idx & 3, l = (idx >> 2) & 63, t = idx >> 8;
    int NT = NC / 16;
    int kt = t / NT, nt = t % NT;
    int k = kt * 32 + (l >> 4) * 8 + d * 2;
    int col = nt * 16 + (l & 15);
    float va = B[(size_t)k * NC + col];
    float vb = B[(size_t)(k + 1) * NC + col];
    ushort ha = f2bf(va), hb = f2bf(vb);
    float ra = va - bf2f(ha), rb = vb - bf2f(hb);
    hi[idx] = (uint)ha | ((uint)hb << 16);
    lo[idx] = (uint)f2bf(ra) | ((uint)f2bf(rb) << 16);
}

__global__ void zero_int(int* __restrict__ p, int n) {
    int idx = blockIdx.x * 256 + threadIdx.x;
    if (idx < n) p[idx] = 0;
}

// ---------------- bucketed CSR build ----------------

__global__ __launch_bounds__(256) void bin_count(const int* __restrict__ edges,
                                                 int* __restrict__ gcount,
                                                 int E, int N, int nbuck) {
    __shared__ int h[1024];
    int tid = threadIdx.x;
    int t = blockIdx.x >> 5, b = blockIdx.x & 31;
    int ce = (E + BPT - 1) / BPT;
    int e0 = b * ce, e1 = min(e0 + ce, E);
    for (int i = tid; i < 1024; i += 256) h[i] = 0;
    __syncthreads();
    const int* dstp = edges + (size_t)t * 2 * E + E;
    for (int i = e0 + tid; i < e1; i += 256) {
        int gid = t * N + dstp[i];
        atomicAdd(&h[gid >> BUCKR_SHIFT], 1);
    }
    __syncthreads();
    for (int i = tid; i < nbuck; i += 256) {
        int c = h[i];
        if (c) atomicAdd(&gcount[i], c);
    }
}

__global__ __launch_bounds__(1024) void scan_buckets(const int* __restrict__ gcount,
                                                     int* __restrict__ bucket_start,
                                                     int* __restrict__ bucket_cursor,
                                                     int nbuck, int* __restrict__ row_start,
                                                     int nTotal, int totalE) {
    __shared__ int s[1024];
    int t = threadIdx.x;
    int own = (t < nbuck) ? gcount[t] : 0;
    s[t] = own; __syncthreads();
    for (int off = 1; off < 1024; off <<= 1) {
        int add = (t >= off) ? s[t - off] : 0;
        __syncthreads();
        s[t] += add;
        __syncthreads();
    }
    if (t < nbuck) {
        int excl = s[t] - own;
        bucket_start[t] = excl;
        bucket_cursor[t] = excl;
    }
    if (t == 0) {
        bucket_start[nbuck] = totalE;
        row_start[nTotal] = totalE;
    }
}

__global__ __launch_bounds__(256) void bin_scatter(const int* __restrict__ edges,
                                                   int* __restrict__ bucket_cursor,
                                                   uint2* __restrict__ staged,
                                                   int E, int N, int nbuck) {
    __shared__ int h[1024];
    __shared__ int base[1024];
    int tid = threadIdx.x;
    int t = blockIdx.x >> 5, b = blockIdx.x & 31;
    int ce = (E + BPT - 1) / BPT;
    int e0 = b * ce, e1 = min(e0 + ce, E);
    for (int i = tid; i < 1024; i += 256) h[i] = 0;
    __syncthreads();
    const int* srcp = edges + (size_t)t * 2 * E;
    const int* dstp = srcp + E;
    for (int i = e0 + tid; i < e1; i += 256) {
        int gid = t * N + dstp[i];
        atomicAdd(&h[gid >> BUCKR_SHIFT], 1);
    }
    __syncthreads();
    for (int i = tid; i < nbuck; i += 256) {
        int c = h[i];
        if (c) base[i] = atomicAdd(&bucket_cursor[i], c);
        h[i] = 0;
    }
    __syncthreads();
    for (int i = e0 + tid; i < e1; i += 256) {
        int sgid = t * N + srcp[i];
        int dgid = t * N + dstp[i];
        int bk = dgid >> BUCKR_SHIFT;
        int loc = atomicAdd(&h[bk], 1);
        staged[base[bk] + loc] = make_uint2((uint)sgid, (uint)dgid);
    }
}

__global__ __launch_bounds__(256) void bin_csr(const uint2* __restrict__ staged,
                                               const int* __restrict__ bucket_start,
                                               int* __restrict__ row_start,
                                               int* __restrict__ csr_src,
                                               float* __restrict__ dinv, int nTotal) {
    __shared__ int cnt[BUCKR];
    __shared__ int part[256];
    int tid = threadIdx.x;
    int node0 = blockIdx.x << BUCKR_SHIFT;
    int nloc = min(BUCKR, nTotal - node0);
    int ebase = bucket_start[blockIdx.x], eend = bucket_start[blockIdx.x + 1];

    for (int j = tid; j < BUCKR; j += 256) cnt[j] = 0;
    __syncthreads();
    for (int e = ebase + tid; e < eend; e += 256)
        atomicAdd(&cnt[(int)staged[e].y - node0], 1);
    __syncthreads();

    int s = 0;
    #pragma unroll
    for (int k = 0; k < 8; k++) s += cnt[tid * 8 + k];
    part[tid] = s; __syncthreads();
    for (int off = 1; off < 256; off <<= 1) {
        int add = (tid >= off) ? part[tid - off] : 0;
        __syncthreads();
        part[tid] += add;
        __syncthreads();
    }
    int run = part[tid] - s;
    #pragma unroll
    for (int k = 0; k < 8; k++) {
        int j = tid * 8 + k;
        int c = cnt[j];
        if (j < nloc) {
            row_start[node0 + j] = ebase + run;
            dinv[node0 + j] = rsqrtf((float)(c + 1));
        }
        cnt[j] = run;
        run += c;
    }
    __syncthreads();
    for (int e = ebase + tid; e < eend; e += 256) {
        uint2 ed = staged[e];
        int d = (int)ed.y - node0;
        int pos = ebase + atomicAdd(&cnt[d], 1);
        csr_src[pos] = (int)ed.x;
    }
}

// ---------------- gather aggregation (hi-only bf16 in/out) ----------------

__global__ __launch_bounds__(256) void agg_gather_t(
    const int* __restrict__ row_start, const int* __restrict__ csr_src,
    const uint* __restrict__ xh,
    const float* __restrict__ dinv, const float* __restrict__ bias,
    uint* __restrict__ ohi, int rowOff, int outRowOff, int nloc)
{
    int w = (blockIdx.x * 256 + threadIdx.x) >> 6;
    int lane = threadIdx.x & 63;
    if (w >= nloc) return;
    int wg = rowOff + w;
    float dr = dinv[wg];
    float cc = dr * dr;
    uint shv = xh[(size_t)wg * 64 + lane];
    float a0 = __uint_as_float(shv << 16) * cc;
    float a1 = __uint_as_float(shv & 0xFFFF0000u) * cc;
    int e = row_start[wg], e1 = row_start[wg + 1];
    for (; e + 4 <= e1; e += 4) {
        int s0 = csr_src[e], s1 = csr_src[e + 1], s2 = csr_src[e + 2], s3 = csr_src[e + 3];
        float c0 = dinv[s0] * dr, c1 = dinv[s1] * dr, c2 = dinv[s2] * dr, c3 = dinv[s3] * dr;
        uint u0 = xh[(size_t)s0 * 64 + lane];
        uint u1 = xh[(size_t)s1 * 64 + lane];
        uint u2 = xh[(size_t)s2 * 64 + lane];
        uint u3 = xh[(size_t)s3 * 64 + lane];
        a0 = fmaf(__uint_as_float(u0 << 16), c0, a0);
        a1 = fmaf(__uint_as_float(u0 & 0xFFFF0000u), c0, a1);
        a0 = fmaf(__uint_as_float(u1 << 16), c1, a0);
        a1 = fmaf(__uint_as_float(u1 & 0xFFFF0000u), c1, a1);
        a0 = fmaf(__uint_as_float(u2 << 16), c2, a0);
        a1 = fmaf(__uint_as_float(u2 & 0xFFFF0000u), c2, a1);
        a0 = fmaf(__uint_as_float(u3 << 16), c3, a0);
        a1 = fmaf(__uint_as_float(u3 & 0xFFFF0000u), c3, a1);
    }
    for (; e < e1; e++) {
        int s = csr_src[e];
        float cf = dinv[s] * dr;
        uint u = xh[(size_t)s * 64 + lane];
        a0 = fmaf(__uint_as_float(u << 16), cf, a0);
        a1 = fmaf(__uint_as_float(u & 0xFFFF0000u), cf, a1);
    }
    float2 b = ((const float2*)bias)[lane];
    a0 = fmaxf(a0 + b.x, 0.f);
    a1 = fmaxf(a1 + b.y, 0.f);
    ohi[(size_t)(wg - outRowOff) * 64 + lane] = (uint)f2bf(a0) | ((uint)f2bf(a1) << 16);
}

// ---------------- MFMA GEMM: [M,128] @ [128,128] -> bf16 hi-only out ----------------
// 512 threads, 128 rows/block, 8 waves = 4(M) x 2(N). A hi-only; B hi+lo (2 MFMAs).

template<bool SPLITSRC>
__global__ __launch_bounds__(512) void gemm_mfma128(
    const float* __restrict__ A32, const ushort* __restrict__ Ahi,
    const uint4* __restrict__ Bhi, const uint4* __restrict__ Blo,
    ushort* __restrict__ Chi, int nrows)
{
    __shared__ ushort AsH[128][136];
    const int r0 = blockIdx.x * 128;
    const int tid = threadIdx.x;

    if (SPLITSRC) {
        for (int v = tid; v < 128 * 16; v += 512) {
            int row = v >> 4, seg = v & 15;
            uint4 h = make_uint4(0, 0, 0, 0);
            if (r0 + row < nrows)
                h = *(const uint4*)(Ahi + (size_t)(r0 + row) * 128 + seg * 8);
            *(uint4*)&AsH[row][seg * 8] = h;
        }
    } else {
        for (int v = tid; v < 128 * 16; v += 512) {
            int row = v >> 4, seg = v & 15;
            float4 a = make_float4(0.f, 0.f, 0.f, 0.f), b = a;
            if (r0 + row < nrows) {
                const float4* src = (const float4*)A32 + (size_t)(r0 + row) * 32 + seg * 2;
                a = src[0]; b = src[1];
            }
            float vv[8] = {a.x, a.y, a.z, a.w, b.x, b.y, b.z, b.w};
            uint hh[4];
            #pragma unroll
            for (int i = 0; i < 4; i++)
                hh[i] = (uint)f2bf(vv[2 * i]) | ((uint)f2bf(vv[2 * i + 1]) << 16);
            *(uint4*)&AsH[row][seg * 8] = make_uint4(hh[0], hh[1], hh[2], hh[3]);
        }
    }
    __syncthreads();

    const int l = tid & 63, w = tid >> 6;
    const int wm = w & 3, wn = w >> 2;
    const int lrow = l & 15, lk = (l >> 4) * 8;

    f32x4 acc[2][4];
    #pragma unroll
    for (int m = 0; m < 2; m++)
        #pragma unroll
        for (int p = 0; p < 4; p++) acc[m][p] = (f32x4){0.f, 0.f, 0.f, 0.f};

    #pragma unroll
    for (int kt = 0; kt < 4; kt++) {
        uint4 BH[4], BL[4];
        #pragma unroll
        for (int p = 0; p < 4; p++) {
            int nt = 4 * wn + p;
            BH[p] = Bhi[(kt * 8 + nt) * 64 + l];
            BL[p] = Blo[(kt * 8 + nt) * 64 + l];
        }
        s8 aH[2];
        #pragma unroll
        for (int m = 0; m < 2; m++) {
            int row = (2 * wm + m) * 16 + lrow;
            aH[m] = *(const s8*)&AsH[row][kt * 32 + lk];
        }
        #pragma unroll
        for (int p = 0; p < 4; p++) {
            s8 bh = __builtin_bit_cast(s8, BH[p]);
            s8 bl = __builtin_bit_cast(s8, BL[p]);
            #pragma unroll
            for (int m = 0; m < 2; m++) {
                acc[m][p] = __builtin_amdgcn_mfma_f32_16x16x32_bf16(aH[m], bh, acc[m][p], 0, 0, 0);
                acc[m][p] = __builtin_amdgcn_mfma_f32_16x16x32_bf16(aH[m], bl, acc[m][p], 0, 0, 0);
            }
        }
    }

    // repack C (hi only) through LDS for coalesced stores
    __syncthreads();
    const int lr4 = (l >> 4) * 4;
    #pragma unroll
    for (int m = 0; m < 2; m++) {
        #pragma unroll
        for (int p = 0; p < 4; p++) {
            int col = (4 * wn + p) * 16 + lrow;
            #pragma unroll
            for (int r = 0; r < 4; r++) {
                int row = (2 * wm + m) * 16 + lr4 + r;
                AsH[row][col] = f2bf(acc[m][p][r]);
            }
        }
    }
    __syncthreads();
    for (int v = tid; v < 128 * 16; v += 512) {
        int row = v >> 4, seg = v & 15;
        if (r0 + row < nrows)
            *(uint4*)(Chi + (size_t)(r0 + row) * 128 + seg * 8) = *(const uint4*)&AsH[row][seg * 8];
    }
}

// ---------------- per-timestep LSTM; LAST fuses head + outputs ----------------
// 512 threads, 64 rows/block, 8 waves; A hi-only bf16; weights hi+lo (2 MFMAs).

template<bool LAST>
__global__ __launch_bounds__(512, 2) void lstm_step_t(
    const ushort* __restrict__ Ehi, ushort* __restrict__ Hhi,
    const uint4* __restrict__ Bhi, const uint4* __restrict__ Blo,
    const float* __restrict__ bsum, float* __restrict__ cbuf,
    const uint4* __restrict__ Whi, const uint4* __restrict__ Wlo,
    const float* __restrict__ bout,
    float* __restrict__ outp, float* __restrict__ outh, float* __restrict__ outc,
    int nrows)
{
    __shared__ ushort AsH[64][264];
    const int r0 = blockIdx.x * 64;
    const int tid = threadIdx.x;
    const int l = tid & 63, w = tid >> 6;          // w in 0..7
    const int lrow = l & 15, lk = (l >> 4) * 8, lr4 = (l >> 4) * 4;

    for (int v = tid; v < 64 * 32; v += 512) {
        int row = v >> 5, seg = v & 31;
        uint4 h = make_uint4(0, 0, 0, 0);
        if (r0 + row < nrows) {
            if (seg < 16)
                h = *(const uint4*)(Ehi + (size_t)(r0 + row) * 128 + seg * 8);
            else
                h = *(const uint4*)(Hhi + (size_t)(r0 + row) * 128 + (seg - 16) * 8);
        }
        *(uint4*)&AsH[row][seg * 8] = h;
    }
    __syncthreads();

    f32x4 acc[4][4];
    #pragma unroll
    for (int m = 0; m < 4; m++)
        #pragma unroll
        for (int q = 0; q < 4; q++) {
            float b = bsum[q * 128 + 16 * w + lrow];
            acc[m][q] = (f32x4){b, b, b, b};
        }

    #pragma unroll 2
    for (int kt = 0; kt < 8; kt++) {
        uint4 BH[4], BL[4];
        #pragma unroll
        for (int q = 0; q < 4; q++) {
            int nt = 8 * q + w;
            BH[q] = Bhi[((size_t)kt * 32 + nt) * 64 + l];
            BL[q] = Blo[((size_t)kt * 32 + nt) * 64 + l];
        }
        s8 aH[4];
        #pragma unroll
        for (int m = 0; m < 4; m++) {
            int row = m * 16 + lrow;
            aH[m] = *(const s8*)&AsH[row][kt * 32 + lk];
        }
        #pragma unroll
        for (int q = 0; q < 4; q++) {
            s8 bh = __builtin_bit_cast(s8, BH[q]);
            s8 bl = __builtin_bit_cast(s8, BL[q]);
            #pragma unroll
            for (int m = 0; m < 4; m++) {
                acc[m][q] = __builtin_amdgcn_mfma_f32_16x16x32_bf16(aH[m], bh, acc[m][q], 0, 0, 0);
                acc[m][q] = __builtin_amdgcn_mfma_f32_16x16x32_bf16(aH[m], bl, acc[m][q], 0, 0, 0);
            }
        }
    }
    if (LAST) __syncthreads();

    #pragma unroll
    for (int m = 0; m < 4; m++) {
        int hh = 16 * w + lrow;
        #pragma unroll
        for (int r = 0; r < 4; r++) {
            int row = m * 16 + lr4 + r;
            if (r0 + row < nrows) {
                size_t o = (size_t)(r0 + row) * HDIM + hh;
                float gi = acc[m][0][r], gf = acc[m][1][r];
                float gg = acc[m][2][r], go = acc[m][3][r];
                float cn = sigmf(gf) * cbuf[o] + sigmf(gi) * fast_tanh(gg);
                float hn = sigmf(go) * fast_tanh(cn);
                cbuf[o] = cn;
                ushort hb = f2bf(hn);
                Hhi[o] = hb;
                if (LAST) {
                    outh[o] = hn;
                    outc[o] = cn;
                    AsH[row][128 + hh] = hb;
                }
            }
        }
    }

    if (LAST) {
        __syncthreads();
        if (w < 4) {
            f32x4 hacc[4];
            {
                float b = bout[w * 16 + lrow];
                #pragma unroll
                for (int m = 0; m < 4; m++) hacc[m] = (f32x4){b, b, b, b};
            }
            #pragma unroll
            for (int kt = 0; kt < 4; kt++) {
                uint4 BH = Whi[(kt * 4 + w) * 64 + l];
                uint4 BL = Wlo[(kt * 4 + w) * 64 + l];
                s8 aH[4];
                #pragma unroll
                for (int m = 0; m < 4; m++) {
                    int row = m * 16 + lrow;
                    aH[m] = *(const s8*)&AsH[row][128 + kt * 32 + lk];
                }
                s8 bh = __builtin_bit_cast(s8, BH);
                s8 bl = __builtin_bit_cast(s8, BL);
                #pragma unroll
                for (int m = 0; m < 4; m++) {
                    hacc[m] = __builtin_amdgcn_mfma_f32_16x16x32_bf16(aH[m], bh, hacc[m], 0, 0, 0);
                    hacc[m] = __builtin_amdgcn_mfma_f32_16x16x32_bf16(aH[m], bl, hacc[m], 0, 0, 0);
                }
            }
            #pragma unroll
            for (int m = 0; m < 4; m++) {
                #pragma unroll
                for (int r = 0; r < 4; r++) {
                    int row = r0 + m * 16 + lr4 + r;
                    if (row < nrows)
                        outp[(size_t)row * ODIM + w * 16 + lrow] = hacc[m][r];
                }
            }
        }
    }
}

// ---------------- launch ----------------

static inline int cdiv(long long a, long long b) { return (int)((a + b - 1) / b); }

extern "C" void kernel_launch(void* const* d_in, const int* in_sizes, int n_in,
                              void* d_out, int out_size, void* d_ws, size_t ws_size,
                              hipStream_t stream) {
    const float* x_seq = (const float*)d_in[0];
    const int*   edges = (const int*)d_in[1];
    const float* W1    = (const float*)d_in[2];
    const float* b1    = (const float*)d_in[3];
    const float* W2    = (const float*)d_in[4];
    const float* b2    = (const float*)d_in[5];
    const float* Wih   = (const float*)d_in[6];
    const float* Whh   = (const float*)d_in[7];
    const float* bih   = (const float*)d_in[8];
    const float* bhh   = (const float*)d_in[9];
    const float* Wout  = (const float*)d_in[10];
    const float* bout  = (const float*)d_in[11];
    float* out = (float*)d_out;

    const int N = in_sizes[0] / (TSTEPS * FDIM);   // 50000
    const int E = in_sizes[1] / (2 * TSTEPS);      // 600000
    const int NT8 = TSTEPS * N;                    // 400000
    const size_t NP = ((size_t)NT8 + 255) & ~(size_t)255;
    const int NBUCK = cdiv(NT8, BUCKR);            // 196
    const size_t nf = (size_t)N * FDIM;
    const int E8 = TSTEPS * E;

    // workspace layout
    float* ws = (float*)d_ws;
    float* dinv = ws;                              // NP f32
    float* wcat = dinv + NP;                       // 256*512
    float* bsum = wcat + 131072;                   // 512
    uint* pW1hi = (uint*)(bsum + 512);             // 8192 each
    uint* pW1lo = pW1hi + 8192;
    uint* pW2hi = pW1lo + 8192;
    uint* pW2lo = pW2hi + 8192;
    uint* pWchi = pW2lo + 8192;                    // 65536 each
    uint* pWclo = pWchi + 65536;
    uint* pWohi = pWclo + 65536;                   // 4096 each
    uint* pWolo = pWohi + 4096;
    float* cbuf = (float*)(pWolo + 4096);          // [N][128] f32
    ushort* hhi = (ushort*)(cbuf + nf);            // [N][128] bf16
    ushort* ehi = hhi + nf;                        // reused slice [2N][128]
    ushort* xwhi = ehi + 2 * nf;                   // [8N][128] hi-only
    ushort* h1hi = xwhi + (size_t)NT8 * 128;       // [8N][128] hi-only
    uint2* staged  = (uint2*)(h1hi + (size_t)NT8 * 128);  // 8E uint2
    int* csr_src   = (int*)(staged + E8);                 // 8E
    int* row_start = csr_src + E8;                        // NT8+1 (pad NP+2)
    int* gcount    = row_start + NP + 2;                  // 1024
    int* bucket_start  = gcount + 1024;                   // 1026
    int* bucket_cursor = bucket_start + 1026;             // 1024

    // weights prep
    prep_lstm_w<<<cdiv(256 * GDIM, 256), 256, 0, stream>>>(Wih, Whh, bih, bhh, wcat, bsum);
    pack_b<<<32, 256, 0, stream>>>(W1, 128, 128, pW1hi, pW1lo);
    pack_b<<<32, 256, 0, stream>>>(W2, 128, 128, pW2hi, pW2lo);
    pack_b<<<256, 256, 0, stream>>>(wcat, 256, GDIM, pWchi, pWclo);
    pack_b<<<16, 256, 0, stream>>>(Wout, 128, ODIM, pWohi, pWolo);

    // zero c (f32, nf ints) + h hi (nf/2 ints)
    zero_int<<<cdiv((long long)nf + nf / 2, 256), 256, 0, stream>>>((int*)cbuf, (int)(nf + nf / 2));

    // bucketed CSR build
    zero_int<<<4, 256, 0, stream>>>(gcount, 1024);
    bin_count<<<TSTEPS * BPT, 256, 0, stream>>>(edges, gcount, E, N, NBUCK);
    scan_buckets<<<1, 1024, 0, stream>>>(gcount, bucket_start, bucket_cursor, NBUCK,
                                         row_start, NT8, E8);
    bin_scatter<<<TSTEPS * BPT, 256, 0, stream>>>(edges, bucket_cursor, staged, E, N, NBUCK);
    bin_csr<<<NBUCK, 256, 0, stream>>>(staged, bucket_start, row_start, csr_src, dinv, NT8);

    const int gagrid2 = cdiv((long long)N * 2 * 64, 256);

    // layer 1: batched GEMM (hi-only out), gathers 2 timesteps per dispatch
    gemm_mfma128<false><<<cdiv(NT8, 128), 512, 0, stream>>>(
        x_seq, nullptr, (const uint4*)pW1hi, (const uint4*)pW1lo, xwhi, NT8);
    for (int tp = 0; tp < 4; tp++)
        agg_gather_t<<<gagrid2, 256, 0, stream>>>(
            row_start, csr_src, (const uint*)xwhi, dinv, b1,
            (uint*)h1hi, tp * 2 * N, 0, 2 * N);

    // layer 2: batched GEMM (hi-only out)
    gemm_mfma128<true><<<cdiv(NT8, 128), 512, 0, stream>>>(
        nullptr, h1hi, (const uint4*)pW2hi, (const uint4*)pW2lo, xwhi, NT8);

    // interleaved: agg2 for 2 timesteps -> lstm(t), lstm(t+1)
    float* out_h = out + (size_t)N * ODIM;
    float* out_c = out_h + (size_t)N * HDIM;
    for (int tp = 0; tp < 4; tp++) {
        agg_gather_t<<<gagrid2, 256, 0, stream>>>(
            row_start, csr_src, (const uint*)xwhi, dinv, b2,
            (uint*)ehi, tp * 2 * N, tp * 2 * N, 2 * N);
        for (int k = 0; k < 2; k++) {
            int t = 2 * tp + k;
            const ushort* eslice = ehi + (size_t)k * nf;
            if (t < TSTEPS - 1) {
                lstm_step_t<false><<<cdiv(N, 64), 512, 0, stream>>>(
                    eslice, hhi, (const uint4*)pWchi, (const uint4*)pWclo, bsum, cbuf,
                    nullptr, nullptr, nullptr, nullptr, nullptr, nullptr, N);
            } else {
                lstm_step_t<true><<<cdiv(N, 64), 512, 0, stream>>>(
                    eslice, hhi, (const uint4*)pWchi, (const uint4*)pWclo, bsum, cbuf,
                    (const uint4*)pWohi, (const uint4*)pWolo, bout,
                    out, out_h, out_c, N);
            }
        }
    }
}